// Round 2
// baseline (839.370 us; speedup 1.0000x reference)
//
#include <hip/hip_runtime.h>
#include <cstdint>
#include <cstddef>

#define HW    262144          // 512*512
#define BATCH 4
#define C     64
#define K     19
#define NPIX  (BATCH * HW)    // 1048576
#define NTILE (NPIX / 64)     // 16384
#define TAUINV (1.0f / 0.07f)
#define EPS   1e-12f

// ws layout:
//   +0     unsigned num_pos
//   +4     float    loss_sum
//   +64    float    k0[19*64]
//   +8192  float    k0n[19*64]
//   +65536 unsigned pm[NPIX]    (4 MB, used if ws_size permits)

__device__ __forceinline__ unsigned build_mask(const int* __restrict__ gp) {
    unsigned m = 0;
#pragma unroll
    for (int k = 0; k < K; ++k)
        m |= (gp[(size_t)k * HW] == 1) ? (1u << k) : 0u;
    return m;
}

__device__ __forceinline__ float wave_reduce_f32(float v) {
#pragma unroll
    for (int off = 32; off; off >>= 1) v += __shfl_down(v, off);
    return v;
}

// ---------------- Kernel 0: packed masks + num_pos ------------------------
__global__ __launch_bounds__(256) void k0_mask(
    const int* __restrict__ gt, unsigned* __restrict__ pm,
    unsigned* __restrict__ num_pos)
{
    const int px = blockIdx.x * 256 + threadIdx.x;   // grid covers NPIX exactly
    const int b  = px >> 18;
    const int hw = px & (HW - 1);
    const unsigned m = build_mask(gt + (size_t)b * K * HW + hw);
    pm[px] = m;
    unsigned np = __popc(m);
#pragma unroll
    for (int off = 32; off; off >>= 1) np += __shfl_down(np, off);
    if ((threadIdx.x & 63) == 0) atomicAdd(num_pos, np);
}

// ---------------- Kernel 1: prototypes k0[k][c] ---------------------------
// 256 threads = 4 waves share one 64ch x 64px LDS tile. lane = channel,
// wave w handles pixels [16w, 16w+16). Branch-free masked accumulate:
// sext(bit) & f  ->  v_bfe_i32 + v_and + v_add (3 VALU per (px,k), covers
// all 64 channels per wave instruction). Block-reduce in LDS, wave0 atomics.
__global__ __launch_bounds__(256) void k1_proto(
    const float* __restrict__ feat, const int* __restrict__ gt,
    const unsigned* __restrict__ pm,
    float* __restrict__ k0, unsigned* __restrict__ num_pos)
{
    __shared__ float    sf[64][65];   // 16.6 KB; reused as reduce buffer at end
    __shared__ unsigned msk[64];
    const int tid  = threadIdx.x;
    const int lane = tid & 63;
    const int wv   = tid >> 6;

    float acc[K];
#pragma unroll
    for (int k = 0; k < K; ++k) acc[k] = 0.0f;

    for (int tile = blockIdx.x; tile < NTILE; tile += gridDim.x) {
        const int b   = tile >> 12;
        const int hw0 = (tile & 4095) << 6;

        // ---- masks (threads 0..63, lane = pixel)
        if (tid < 64) {
            unsigned m;
            if (pm) {
                m = pm[(size_t)tile * 64 + tid];
            } else {
                m = build_mask(gt + (size_t)b * K * HW + hw0 + tid);
                unsigned np = __popc(m);
#pragma unroll
                for (int off = 32; off; off >>= 1) np += __shfl_down(np, off);
                if (tid == 0) atomicAdd(num_pos, np);
            }
            msk[tid] = m;
        }

        // ---- stage feat tile: 1024 float4 over 256 threads
        {
            const float* fb = feat + (size_t)b * C * HW + hw0;
#pragma unroll
            for (int i = 0; i < 4; ++i) {
                const int v  = tid + (i << 8);
                const int c  = v >> 4;
                const int p0 = (v & 15) << 2;
                const float4 val = *(const float4*)(fb + (size_t)c * HW + p0);
                sf[c][p0 + 0] = val.x; sf[c][p0 + 1] = val.y;
                sf[c][p0 + 2] = val.z; sf[c][p0 + 3] = val.w;
            }
        }
        __syncthreads();

        // ---- accumulate: lane = channel; 16 pixels per wave
#pragma unroll
        for (int j = 0; j < 16; ++j) {
            const int p = (wv << 4) + j;
            const float    f = sf[lane][p];
            const unsigned m = msk[p];          // broadcast read, stays VGPR
#pragma unroll
            for (int k = 0; k < K; ++k) {
                const int s = ((int)(m << (31 - k))) >> 31;   // 0 or -1
                acc[k] += __int_as_float(s & __float_as_int(f));
            }
        }
        __syncthreads();
    }

    // ---- block reduce through sf (4160 floats >= 3*1216), wave0 atomics
    float* red = &sf[0][0];
    if (wv > 0) {
#pragma unroll
        for (int k = 0; k < K; ++k)
            red[(wv - 1) * (K * 64) + k * 64 + lane] = acc[k];
    }
    __syncthreads();
    if (wv == 0) {
#pragma unroll
        for (int k = 0; k < K; ++k) {
            const float v = acc[k]
                + red[0 * (K * 64) + k * 64 + lane]
                + red[1 * (K * 64) + k * 64 + lane]
                + red[2 * (K * 64) + k * 64 + lane];
            atomicAdd(&k0[k * 64 + lane], v);
        }
    }
}

// ---------------- Kernel 2: normalize prototypes --------------------------
__global__ __launch_bounds__(256) void k2_norm(
    const float* __restrict__ k0, float* __restrict__ k0n)
{
    __shared__ float rn[K];
    const int t = threadIdx.x;
    if (t < K) {
        float s = 0.0f;
        for (int c = 0; c < 64; ++c) { float v = k0[t * 64 + c]; s = fmaf(v, v, s); }
        rn[t] = 1.0f / fmaxf(sqrtf(s), EPS);
    }
    __syncthreads();
    for (int i = t; i < K * 64; i += 256) k0n[i] = k0[i] * rn[i >> 6];
}

// ---------------- Kernel 3: logits + log-softmax + masked NLL -------------
// thread = pixel, fully streaming: coalesced global feat reads (no LDS
// staging, no syncthreads in the hot path). w in LDS, read as uniform
// float4 broadcasts.
__global__ __launch_bounds__(256) void k3_loss(
    const float* __restrict__ feat, const int* __restrict__ gt,
    const unsigned* __restrict__ pm, const float* __restrict__ k0n,
    float* __restrict__ loss_sum)
{
    __shared__ __align__(16) float w[K * 64];
    const int tid = threadIdx.x;
    for (int i = tid; i < K * 64; i += 256) w[i] = k0n[i];
    __syncthreads();

    const int px = blockIdx.x * 256 + tid;           // grid covers NPIX exactly
    const int b  = px >> 18;
    const int hw = px & (HW - 1);
    const float* fb = feat + (size_t)b * C * HW + hw;

    unsigned m;
    if (pm) m = pm[px];
    else    m = build_mask(gt + (size_t)b * K * HW + hw);

    float dot[K];
#pragma unroll
    for (int k = 0; k < K; ++k) dot[k] = 0.0f;
    float ss = 0.0f;

    for (int c = 0; c < 64; c += 4) {
        const float f0 = fb[(size_t)(c + 0) * HW];
        const float f1 = fb[(size_t)(c + 1) * HW];
        const float f2 = fb[(size_t)(c + 2) * HW];
        const float f3 = fb[(size_t)(c + 3) * HW];
        ss = fmaf(f0, f0, fmaf(f1, f1, fmaf(f2, f2, fmaf(f3, f3, ss))));
#pragma unroll
        for (int k = 0; k < K; ++k) {
            const float4 wv = *(const float4*)&w[k * 64 + c];  // uniform b128
            dot[k] = fmaf(wv.x, f0, fmaf(wv.y, f1,
                     fmaf(wv.z, f2, fmaf(wv.w, f3, dot[k]))));
        }
    }

    const float sc = TAUINV / fmaxf(sqrtf(ss), EPS);
    float mx = -1e30f;
#pragma unroll
    for (int k = 0; k < K; ++k) { dot[k] *= sc; mx = fmaxf(mx, dot[k]); }
    float se = 0.0f;
#pragma unroll
    for (int k = 0; k < K; ++k) se += expf(dot[k] - mx);
    const float logZ = mx + logf(se);

    float ls = (float)__popc(m) * logZ;
#pragma unroll
    for (int k = 0; k < K; ++k) {
        const int s = ((int)(m << (31 - k))) >> 31;            // 0 or -1
        ls -= __int_as_float(s & __float_as_int(dot[k]));
    }

    ls = wave_reduce_f32(ls);
    if ((tid & 63) == 0) atomicAdd(loss_sum, ls);
}

// ---------------- Kernel 4: finalize --------------------------------------
__global__ void k4_final(const float* __restrict__ loss_sum,
                         const unsigned* __restrict__ num_pos,
                         float* __restrict__ out)
{
    out[0] = loss_sum[0] / (float)num_pos[0];
}

// ---------------- launch ---------------------------------------------------
extern "C" void kernel_launch(void* const* d_in, const int* in_sizes, int n_in,
                              void* d_out, int out_size, void* d_ws, size_t ws_size,
                              hipStream_t stream)
{
    const float* feat = (const float*)d_in[0];
    const int*   gt   = (const int*)d_in[1];
    float*       out  = (float*)d_out;

    char* ws = (char*)d_ws;
    unsigned* num_pos  = (unsigned*)(ws + 0);
    float*    loss_sum = (float*)(ws + 4);
    float*    k0       = (float*)(ws + 64);
    float*    k0n      = (float*)(ws + 8192);
    unsigned* pm       = nullptr;
    if (ws_size >= 65536 + sizeof(unsigned) * (size_t)NPIX)
        pm = (unsigned*)(ws + 65536);

    hipMemsetAsync(d_ws, 0, 16384, stream);  // zero num_pos/loss_sum/k0

    if (pm) k0_mask<<<NPIX / 256, 256, 0, stream>>>(gt, pm, num_pos);
    k1_proto<<<2048, 256, 0, stream>>>(feat, gt, pm, k0, num_pos);
    k2_norm <<<1,    256, 0, stream>>>(k0, k0n);
    k3_loss <<<NPIX / 256, 256, 0, stream>>>(feat, gt, pm, k0n, loss_sum);
    k4_final<<<1,    1,   0, stream>>>(loss_sum, num_pos, out);
}

// Round 3
// 562.051 us; speedup vs baseline: 1.4934x; 1.4934x over previous
//
#include <hip/hip_runtime.h>
#include <cstdint>
#include <cstddef>

#define HW    262144          // 512*512
#define C     64
#define K     19
#define NPIX  1048576
#define TAUINV (1.0f / 0.07f)
#define EPS   1e-12f

#define T1    128             // k1 tile pixels
#define NT1   (NPIX / T1)     // 8192 tiles
#define TPB1  (HW / T1)       // 2048 tiles per batch image
#define G1    2048            // k1 grid blocks

// ws layout:
//   +0     unsigned num_pos
//   +4     float    loss_sum
//   +64    float    k0[19*64]
//   +8192  float    k0n[19*64]
//   +65536 unsigned pm[NPIX]   (4 MB, used if ws_size permits)

__device__ __forceinline__ float wave_reduce_f32(float v) {
#pragma unroll
    for (int off = 32; off; off >>= 1) v += __shfl_down(v, off);
    return v;
}

__device__ __forceinline__ unsigned wave_reduce_u32(unsigned v) {
#pragma unroll
    for (int off = 32; off; off >>= 1) v += __shfl_down(v, off);
    return v;
}

// ---------------- Kernel 1: masks + num_pos + prototypes k0[k][c] ---------
// 256 thr = 4 waves. 128-px tiles. Register-prefetch double buffer: next
// tile's feat (8x dwordx4) + mask (19 coalesced) loads issue BEFORE the
// current tile's ~4400-cyc VALU accumulate, hiding HBM latency.
__device__ __forceinline__ void k1_prefetch(
    int tile, const float* __restrict__ feat, const int* __restrict__ gt,
    int tid, float4 f[8], unsigned* mpf)
{
    const int b   = tile >> 11;           // /TPB1
    const int hw0 = (tile & (TPB1 - 1)) << 7;
    const float* fb = feat + (size_t)b * C * HW + hw0;
#pragma unroll
    for (int i = 0; i < 8; ++i) {
        const int v  = tid + (i << 8);
        const int c  = v >> 5;            // 32 float4 per 128-px row
        const int p0 = (v & 31) << 2;
        f[i] = *(const float4*)(fb + (size_t)c * HW + p0);
    }
    if (tid < T1) {                       // waves 0,1 exactly — no divergence
        const int* gp = gt + (size_t)b * K * HW + hw0 + tid;
        unsigned m = 0;
#pragma unroll
        for (int k = 0; k < K; ++k)
            m |= (gp[(size_t)k * HW] == 1) ? (1u << k) : 0u;
        *mpf = m;
    }
}

__global__ __launch_bounds__(256) void k1_proto(
    const float* __restrict__ feat, const int* __restrict__ gt,
    unsigned* __restrict__ pm,
    float* __restrict__ k0, unsigned* __restrict__ num_pos)
{
    __shared__ float    sf[64][129];      // stride 129 -> (c+p)%32, 2-way free
    __shared__ unsigned msk[T1];
    const int tid  = threadIdx.x;
    const int lane = tid & 63;
    const int wv   = tid >> 6;

    float acc[K];
#pragma unroll
    for (int k = 0; k < K; ++k) acc[k] = 0.0f;
    unsigned npos = 0;

    float4   f[8];
    unsigned mpf = 0;
    int tile = blockIdx.x;
    if (tile < NT1) k1_prefetch(tile, feat, gt, tid, f, &mpf);

    for (; tile < NT1; ) {
        if (tid < T1) {
            msk[tid] = mpf;
            if (pm) pm[(size_t)tile * T1 + tid] = mpf;
            npos += __popc(mpf);
        }
        // stage current tile's registers into LDS (4x b32 each, padded rows)
#pragma unroll
        for (int i = 0; i < 8; ++i) {
            const int v  = tid + (i << 8);
            const int c  = v >> 5;
            const int p0 = (v & 31) << 2;
            sf[c][p0 + 0] = f[i].x; sf[c][p0 + 1] = f[i].y;
            sf[c][p0 + 2] = f[i].z; sf[c][p0 + 3] = f[i].w;
        }
        __syncthreads();

        const int nxt = tile + G1;
        if (nxt < NT1) k1_prefetch(nxt, feat, gt, tid, f, &mpf);

        // accumulate: lane = channel; this wave's 32 pixels
#pragma unroll 4
        for (int p = 0; p < 32; ++p) {
            const int pp = (wv << 5) + p;
            const float    fv = sf[lane][pp];
            const unsigned m  = msk[pp];
#pragma unroll
            for (int k = 0; k < K; ++k) {
                const int s = ((int)(m << (31 - k))) >> 31;   // v_bfe_i32
                acc[k] += __int_as_float(s & __float_as_int(fv));
            }
        }
        __syncthreads();
        tile = nxt;
    }

    // block reduce via sf (needs 3*1216 <= 8256 floats), wave0 atomics
    float* red = &sf[0][0];
    if (wv > 0) {
#pragma unroll
        for (int k = 0; k < K; ++k)
            red[(wv - 1) * (K * 64) + k * 64 + lane] = acc[k];
    }
    __syncthreads();
    if (wv == 0) {
#pragma unroll
        for (int k = 0; k < K; ++k) {
            const float v = acc[k]
                + red[0 * (K * 64) + k * 64 + lane]
                + red[1 * (K * 64) + k * 64 + lane]
                + red[2 * (K * 64) + k * 64 + lane];
            atomicAdd(&k0[k * 64 + lane], v);
        }
    }
    const unsigned np = wave_reduce_u32(npos);   // waves 2,3 contribute 0
    if (lane == 0) atomicAdd(num_pos, np);
}

// ---------------- Kernel 2: normalize prototypes --------------------------
__global__ __launch_bounds__(256) void k2_norm(
    const float* __restrict__ k0, float* __restrict__ k0n)
{
    __shared__ float rn[K];
    const int tid  = threadIdx.x;
    const int lane = tid & 63;
    const int wv   = tid >> 6;
    for (int cls = wv; cls < K; cls += 4) {
        const float v = k0[cls * 64 + lane];
        const float s = wave_reduce_f32(v * v);
        if (lane == 0) rn[cls] = 1.0f / fmaxf(sqrtf(s), EPS);
    }
    __syncthreads();
    for (int i = tid; i < K * 64; i += 256) k0n[i] = k0[i] * rn[i >> 6];
}

// ---------------- Kernel 3: logits + log-softmax + masked NLL -------------
// thread = 4 consecutive pixels: feat loads are dwordx4 (4 KB/wave-load),
// manual 2-stage pipeline keeps 8 loads (32 KB/wave) in flight under the
// 608-FMA compute block per channel group.
__global__ __launch_bounds__(256) void k3_loss(
    const float* __restrict__ feat, const int* __restrict__ gt,
    const unsigned* __restrict__ pm, const float* __restrict__ k0n,
    float* __restrict__ loss_sum)
{
    __shared__ __align__(16) float w[K * 64];
    const int tid = threadIdx.x;
    for (int i = tid; i < K * 64; i += 256) w[i] = k0n[i];
    __syncthreads();

    const int px0 = (blockIdx.x * 256 + tid) << 2;
    const int b   = px0 >> 18;
    const int hw  = px0 & (HW - 1);
    const float* fb = feat + (size_t)b * C * HW + hw;

    unsigned marr[4];
    if (pm) {
        const uint4 mv = *(const uint4*)(pm + px0);
        marr[0] = mv.x; marr[1] = mv.y; marr[2] = mv.z; marr[3] = mv.w;
    } else {
        marr[0] = marr[1] = marr[2] = marr[3] = 0;
        const int* gp = gt + (size_t)b * K * HW + hw;
#pragma unroll
        for (int k = 0; k < K; ++k) {
            const int4 g4 = *(const int4*)(gp + (size_t)k * HW);
            marr[0] |= (g4.x == 1) ? (1u << k) : 0u;
            marr[1] |= (g4.y == 1) ? (1u << k) : 0u;
            marr[2] |= (g4.z == 1) ? (1u << k) : 0u;
            marr[3] |= (g4.w == 1) ? (1u << k) : 0u;
        }
    }

    float4 dot[K];
#pragma unroll
    for (int k = 0; k < K; ++k) dot[k] = make_float4(0.f, 0.f, 0.f, 0.f);
    float4 ss = make_float4(0.f, 0.f, 0.f, 0.f);

    float4 f[8];
#pragma unroll
    for (int j = 0; j < 8; ++j)
        f[j] = *(const float4*)(fb + (size_t)j * HW);

#pragma unroll
    for (int cg = 0; cg < 64; cg += 8) {
        float4 g[8];
        if (cg + 8 < 64) {
#pragma unroll
            for (int j = 0; j < 8; ++j)
                g[j] = *(const float4*)(fb + (size_t)(cg + 8 + j) * HW);
        }
#pragma unroll
        for (int j = 0; j < 8; ++j) {
            const float4 fv = f[j];
            ss.x = fmaf(fv.x, fv.x, ss.x); ss.y = fmaf(fv.y, fv.y, ss.y);
            ss.z = fmaf(fv.z, fv.z, ss.z); ss.w = fmaf(fv.w, fv.w, ss.w);
        }
#pragma unroll
        for (int k = 0; k < K; ++k) {
            const float4 wa = *(const float4*)&w[k * 64 + cg];
            const float4 wb = *(const float4*)&w[k * 64 + cg + 4];
            float4 d = dot[k];
            d.x = fmaf(f[0].x, wa.x, d.x); d.y = fmaf(f[0].y, wa.x, d.y);
            d.z = fmaf(f[0].z, wa.x, d.z); d.w = fmaf(f[0].w, wa.x, d.w);
            d.x = fmaf(f[1].x, wa.y, d.x); d.y = fmaf(f[1].y, wa.y, d.y);
            d.z = fmaf(f[1].z, wa.y, d.z); d.w = fmaf(f[1].w, wa.y, d.w);
            d.x = fmaf(f[2].x, wa.z, d.x); d.y = fmaf(f[2].y, wa.z, d.y);
            d.z = fmaf(f[2].z, wa.z, d.z); d.w = fmaf(f[2].w, wa.z, d.w);
            d.x = fmaf(f[3].x, wa.w, d.x); d.y = fmaf(f[3].y, wa.w, d.y);
            d.z = fmaf(f[3].z, wa.w, d.z); d.w = fmaf(f[3].w, wa.w, d.w);
            d.x = fmaf(f[4].x, wb.x, d.x); d.y = fmaf(f[4].y, wb.x, d.y);
            d.z = fmaf(f[4].z, wb.x, d.z); d.w = fmaf(f[4].w, wb.x, d.w);
            d.x = fmaf(f[5].x, wb.y, d.x); d.y = fmaf(f[5].y, wb.y, d.y);
            d.z = fmaf(f[5].z, wb.y, d.z); d.w = fmaf(f[5].w, wb.y, d.w);
            d.x = fmaf(f[6].x, wb.z, d.x); d.y = fmaf(f[6].y, wb.z, d.y);
            d.z = fmaf(f[6].z, wb.z, d.z); d.w = fmaf(f[6].w, wb.z, d.w);
            d.x = fmaf(f[7].x, wb.w, d.x); d.y = fmaf(f[7].y, wb.w, d.y);
            d.z = fmaf(f[7].z, wb.w, d.z); d.w = fmaf(f[7].w, wb.w, d.w);
            dot[k] = d;
        }
        if (cg + 8 < 64) {
#pragma unroll
            for (int j = 0; j < 8; ++j) f[j] = g[j];
        }
    }

    // epilogue: per-pixel normalize, softmax, masked NLL
    float ls = 0.0f;
    float* dp = (float*)&dot[0];          // dp[k*4 + comp], reg-resident
    const float* sp = (const float*)&ss;
#pragma unroll
    for (int comp = 0; comp < 4; ++comp) {
        const float sc = TAUINV / fmaxf(sqrtf(sp[comp]), EPS);
        float mx = -1e30f;
#pragma unroll
        for (int k = 0; k < K; ++k) {
            dp[k * 4 + comp] *= sc;
            mx = fmaxf(mx, dp[k * 4 + comp]);
        }
        float se = 0.0f;
#pragma unroll
        for (int k = 0; k < K; ++k) se += expf(dp[k * 4 + comp] - mx);
        const float logZ = mx + logf(se);
        const unsigned m = marr[comp];
        ls += (float)__popc(m) * logZ;
#pragma unroll
        for (int k = 0; k < K; ++k) {
            const int s = ((int)(m << (31 - k))) >> 31;
            ls -= __int_as_float(s & __float_as_int(dp[k * 4 + comp]));
        }
    }

    ls = wave_reduce_f32(ls);
    if ((tid & 63) == 0) atomicAdd(loss_sum, ls);
}

// ---------------- Kernel 4: finalize --------------------------------------
__global__ void k4_final(const float* __restrict__ loss_sum,
                         const unsigned* __restrict__ num_pos,
                         float* __restrict__ out)
{
    out[0] = loss_sum[0] / (float)num_pos[0];
}

// ---------------- launch ---------------------------------------------------
extern "C" void kernel_launch(void* const* d_in, const int* in_sizes, int n_in,
                              void* d_out, int out_size, void* d_ws, size_t ws_size,
                              hipStream_t stream)
{
    const float* feat = (const float*)d_in[0];
    const int*   gt   = (const int*)d_in[1];
    float*       out  = (float*)d_out;

    char* ws = (char*)d_ws;
    unsigned* num_pos  = (unsigned*)(ws + 0);
    float*    loss_sum = (float*)(ws + 4);
    float*    k0       = (float*)(ws + 64);
    float*    k0n      = (float*)(ws + 8192);
    unsigned* pm       = nullptr;
    if (ws_size >= 65536 + sizeof(unsigned) * (size_t)NPIX)
        pm = (unsigned*)(ws + 65536);

    hipMemsetAsync(d_ws, 0, 16384, stream);   // zero num_pos/loss_sum/k0

    k1_proto<<<G1, 256, 0, stream>>>(feat, gt, pm, k0, num_pos);
    k2_norm <<<1,  256, 0, stream>>>(k0, k0n);
    k3_loss <<<NPIX / 1024, 256, 0, stream>>>(feat, gt, pm, k0n, loss_sum);
    k4_final<<<1, 1, 0, stream>>>(loss_sum, num_pos, out);
}

// Round 4
// 536.518 us; speedup vs baseline: 1.5645x; 1.0476x over previous
//
#include <hip/hip_runtime.h>
#include <cstdint>
#include <cstddef>

#define HW    262144          // 512*512
#define C     64
#define K     19
#define NPIX  1048576
#define TAUINV (1.0f / 0.07f)
#define EPS   1e-12f

#define NCHUNK (NPIX / 32)    // 32768 chunks of 32 pixels
#define CPB    8192           // chunks per batch image (HW/32)
#define G1     1024           // k1 blocks (4096 waves -> 8 chunks/wave)

// ws layout:
//   +0     unsigned num_pos
//   +4     float    loss_sum
//   +256   float    k0p[32*64]   (8 KB, classes padded to 32)
//   +8448  float    k0n[19*64]
//   +65536 unsigned pm[NPIX]     (4 MB)

typedef __attribute__((ext_vector_type(8))) short bf16x8;
typedef __attribute__((ext_vector_type(4))) float f32x4;

__device__ __forceinline__ float wave_reduce_f32(float v) {
#pragma unroll
    for (int off = 32; off; off >>= 1) v += __shfl_down(v, off);
    return v;
}
__device__ __forceinline__ unsigned wave_reduce_u32(unsigned v) {
#pragma unroll
    for (int off = 32; off; off >>= 1) v += __shfl_down(v, off);
    return v;
}

// RNE f32 -> (bf16 hi, bf16 lo): hi+lo represents f to ~2^-16 relative
__device__ __forceinline__ void split1(float f, short& h, short& l) {
    const unsigned u  = __float_as_uint(f);
    const unsigned hb = (u + 0x7FFFu + ((u >> 16) & 1u)) & 0xFFFF0000u;
    h = (short)(hb >> 16);
    const float lo = f - __uint_as_float(hb);
    const unsigned v = __float_as_uint(lo);
    l = (short)((v + 0x7FFFu + ((v >> 16) & 1u)) >> 16);
}

// ---------------- Kernel 1: MFMA prototypes k0p[32][64] + masks -----------
// k0[k][c] = sum_px mask[k][px] * feat[c][px]  ==  A(32xK px) * B(K px x 64)
// as 16x16x32 bf16 MFMAs. Mask exact in bf16; feat split hi/lo (2 MFMAs).
// Per 32-px chunk per wave: 19 coalesced gt dwords, 8 feat dwordx4 (direct
// from global, 8 consecutive px per lane = B-fragment layout), 16 MFMAs.
__global__ __launch_bounds__(256) void k1_proto(
    const float* __restrict__ feat, const int* __restrict__ gt,
    unsigned* __restrict__ pm,
    float* __restrict__ k0p, unsigned* __restrict__ num_pos)
{
    __shared__ float red[32 * 64];        // 8 KB block-reduce buffer
    const int tid  = threadIdx.x;
    const int lane = tid & 63;
    const int wv   = tid >> 6;
    const int q    = lane >> 4;           // quad 0..3
    const int n    = lane & 15;           // n/col within fragment
    const int q8   = q << 3;              // this quad's k-offset (pixels)

    f32x4 acc[2][4];
#pragma unroll
    for (int mt = 0; mt < 2; ++mt)
#pragma unroll
        for (int nt = 0; nt < 4; ++nt)
            acc[mt][nt] = (f32x4){0.f, 0.f, 0.f, 0.f};
    unsigned npos = 0;

    const int wave_id = blockIdx.x * 4 + wv;
    const int nwaves  = G1 * 4;

    for (int chunk = wave_id; chunk < NCHUNK; chunk += nwaves) {
        const int b   = chunk >> 13;                 // / CPB
        const int hw0 = (chunk & (CPB - 1)) << 5;
        const size_t fbase = (size_t)b * C * HW + hw0;

        // ---- packed masks: lanes 0..31 own one pixel each (coalesced gt)
        unsigned mymask = 0;
        if (lane < 32) {
            const int* gp = gt + (size_t)b * K * HW + hw0 + lane;
#pragma unroll
            for (int k = 0; k < K; ++k)
                mymask |= (gp[(size_t)k * HW] == 1) ? (1u << k) : 0u;
            pm[(size_t)chunk * 32 + lane] = mymask;
            npos += __popc(mymask);
        }

        // ---- A fragments (mask): lane holds class row m=n (tile0) /
        //      n+16 (tile1), k = q8+j. Bits -> bf16 {0, 1.0}.
        unsigned w8[8];
#pragma unroll
        for (int j = 0; j < 8; ++j) w8[j] = __shfl(mymask, q8 + j);
        bf16x8 a0, a1;
#pragma unroll
        for (int j = 0; j < 8; ++j) {
            a0[j] = (short)(((w8[j] >> n) & 1u) * 0x3F80u);
            a1[j] = (short)(((w8[j] >> (n + 16)) & 1u) * 0x3F80u);
        }

        // ---- B fragments (feat hi/lo) + MFMA, per 16-channel N-tile
        const float* fp = feat + fbase + (size_t)n * HW + q8;
#pragma unroll
        for (int nt = 0; nt < 4; ++nt) {
            const float* p = fp + (size_t)(nt * 16) * HW;
            const float4 x = *(const float4*)p;
            const float4 y = *(const float4*)(p + 4);
            bf16x8 bh, bl;
            {
                short h, l;
                split1(x.x, h, l); bh[0] = h; bl[0] = l;
                split1(x.y, h, l); bh[1] = h; bl[1] = l;
                split1(x.z, h, l); bh[2] = h; bl[2] = l;
                split1(x.w, h, l); bh[3] = h; bl[3] = l;
                split1(y.x, h, l); bh[4] = h; bl[4] = l;
                split1(y.y, h, l); bh[5] = h; bl[5] = l;
                split1(y.z, h, l); bh[6] = h; bl[6] = l;
                split1(y.w, h, l); bh[7] = h; bl[7] = l;
            }
            acc[0][nt] = __builtin_amdgcn_mfma_f32_16x16x32_bf16(a0, bh, acc[0][nt], 0, 0, 0);
            acc[0][nt] = __builtin_amdgcn_mfma_f32_16x16x32_bf16(a0, bl, acc[0][nt], 0, 0, 0);
            acc[1][nt] = __builtin_amdgcn_mfma_f32_16x16x32_bf16(a1, bh, acc[1][nt], 0, 0, 0);
            acc[1][nt] = __builtin_amdgcn_mfma_f32_16x16x32_bf16(a1, bl, acc[1][nt], 0, 0, 0);
        }
    }

    // ---- block reduce (D layout: class = mt*16 + q*4 + r, ch = nt*16 + n)
    for (int w = 0; w < 4; ++w) {
        if (wv == w) {
#pragma unroll
            for (int mt = 0; mt < 2; ++mt)
#pragma unroll
                for (int nt = 0; nt < 4; ++nt)
#pragma unroll
                    for (int r = 0; r < 4; ++r) {
                        const int idx = (mt * 16 + q * 4 + r) * 64 + nt * 16 + n;
                        if (w == 0) red[idx]  = acc[mt][nt][r];
                        else        red[idx] += acc[mt][nt][r];
                    }
        }
        __syncthreads();
    }
    for (int i = tid; i < 32 * 64; i += 256)
        atomicAdd(&k0p[i], red[i]);

    const unsigned np = wave_reduce_u32(npos);
    if (lane == 0) atomicAdd(num_pos, np);
}

// ---------------- Kernel 2: normalize prototypes --------------------------
__global__ __launch_bounds__(256) void k2_norm(
    const float* __restrict__ k0p, float* __restrict__ k0n)
{
    __shared__ float rn[K];
    const int tid  = threadIdx.x;
    const int lane = tid & 63;
    const int wv   = tid >> 6;
    for (int cls = wv; cls < K; cls += 4) {
        const float v = k0p[cls * 64 + lane];
        const float s = wave_reduce_f32(v * v);
        if (lane == 0) rn[cls] = 1.0f / fmaxf(sqrtf(s), EPS);
    }
    __syncthreads();
    for (int i = tid; i < K * 64; i += 256) k0n[i] = k0p[i] * rn[i >> 6];
}

// ---------------- Kernel 3: logits + log-softmax + masked NLL -------------
__global__ __launch_bounds__(256) void k3_loss(
    const float* __restrict__ feat, const int* __restrict__ gt,
    const unsigned* __restrict__ pm, const float* __restrict__ k0n,
    float* __restrict__ loss_sum)
{
    __shared__ __align__(16) float w[K * 64];
    const int tid = threadIdx.x;
    for (int i = tid; i < K * 64; i += 256) w[i] = k0n[i];
    __syncthreads();

    const int px0 = (blockIdx.x * 256 + tid) << 2;
    const int b   = px0 >> 18;
    const int hw  = px0 & (HW - 1);
    const float* fb = feat + (size_t)b * C * HW + hw;

    unsigned marr[4];
    {
        const uint4 mv = *(const uint4*)(pm + px0);
        marr[0] = mv.x; marr[1] = mv.y; marr[2] = mv.z; marr[3] = mv.w;
    }

    float4 dot[K];
#pragma unroll
    for (int k = 0; k < K; ++k) dot[k] = make_float4(0.f, 0.f, 0.f, 0.f);
    float4 ss = make_float4(0.f, 0.f, 0.f, 0.f);

    float4 f[8];
#pragma unroll
    for (int j = 0; j < 8; ++j)
        f[j] = *(const float4*)(fb + (size_t)j * HW);

#pragma unroll
    for (int cg = 0; cg < 64; cg += 8) {
        float4 g[8];
        if (cg + 8 < 64) {
#pragma unroll
            for (int j = 0; j < 8; ++j)
                g[j] = *(const float4*)(fb + (size_t)(cg + 8 + j) * HW);
        }
#pragma unroll
        for (int j = 0; j < 8; ++j) {
            const float4 fv = f[j];
            ss.x = fmaf(fv.x, fv.x, ss.x); ss.y = fmaf(fv.y, fv.y, ss.y);
            ss.z = fmaf(fv.z, fv.z, ss.z); ss.w = fmaf(fv.w, fv.w, ss.w);
        }
#pragma unroll
        for (int k = 0; k < K; ++k) {
            const float4 wa = *(const float4*)&w[k * 64 + cg];
            const float4 wb = *(const float4*)&w[k * 64 + cg + 4];
            float4 d = dot[k];
            d.x = fmaf(f[0].x, wa.x, d.x); d.y = fmaf(f[0].y, wa.x, d.y);
            d.z = fmaf(f[0].z, wa.x, d.z); d.w = fmaf(f[0].w, wa.x, d.w);
            d.x = fmaf(f[1].x, wa.y, d.x); d.y = fmaf(f[1].y, wa.y, d.y);
            d.z = fmaf(f[1].z, wa.y, d.z); d.w = fmaf(f[1].w, wa.y, d.w);
            d.x = fmaf(f[2].x, wa.z, d.x); d.y = fmaf(f[2].y, wa.z, d.y);
            d.z = fmaf(f[2].z, wa.z, d.z); d.w = fmaf(f[2].w, wa.z, d.w);
            d.x = fmaf(f[3].x, wa.w, d.x); d.y = fmaf(f[3].y, wa.w, d.y);
            d.z = fmaf(f[3].z, wa.w, d.z); d.w = fmaf(f[3].w, wa.w, d.w);
            d.x = fmaf(f[4].x, wb.x, d.x); d.y = fmaf(f[4].y, wb.x, d.y);
            d.z = fmaf(f[4].z, wb.x, d.z); d.w = fmaf(f[4].w, wb.x, d.w);
            d.x = fmaf(f[5].x, wb.y, d.x); d.y = fmaf(f[5].y, wb.y, d.y);
            d.z = fmaf(f[5].z, wb.y, d.z); d.w = fmaf(f[5].w, wb.y, d.w);
            d.x = fmaf(f[6].x, wb.z, d.x); d.y = fmaf(f[6].y, wb.z, d.y);
            d.z = fmaf(f[6].z, wb.z, d.z); d.w = fmaf(f[6].w, wb.z, d.w);
            d.x = fmaf(f[7].x, wb.w, d.x); d.y = fmaf(f[7].y, wb.w, d.y);
            d.z = fmaf(f[7].z, wb.w, d.z); d.w = fmaf(f[7].w, wb.w, d.w);
            dot[k] = d;
        }
        if (cg + 8 < 64) {
#pragma unroll
            for (int j = 0; j < 8; ++j) f[j] = g[j];
        }
    }

    float ls = 0.0f;
    float* dp = (float*)&dot[0];
    const float* sp = (const float*)&ss;
#pragma unroll
    for (int comp = 0; comp < 4; ++comp) {
        const float sc = TAUINV / fmaxf(sqrtf(sp[comp]), EPS);
        float mx = -1e30f;
#pragma unroll
        for (int k = 0; k < K; ++k) {
            dp[k * 4 + comp] *= sc;
            mx = fmaxf(mx, dp[k * 4 + comp]);
        }
        float se = 0.0f;
#pragma unroll
        for (int k = 0; k < K; ++k) se += expf(dp[k * 4 + comp] - mx);
        const float logZ = mx + logf(se);
        const unsigned m = marr[comp];
        ls += (float)__popc(m) * logZ;
#pragma unroll
        for (int k = 0; k < K; ++k) {
            const int s = ((int)(m << (31 - k))) >> 31;
            ls -= __int_as_float(s & __float_as_int(dp[k * 4 + comp]));
        }
    }

    ls = wave_reduce_f32(ls);
    if ((tid & 63) == 0) atomicAdd(loss_sum, ls);
}

// ---------------- Kernel 4: finalize --------------------------------------
__global__ void k4_final(const float* __restrict__ loss_sum,
                         const unsigned* __restrict__ num_pos,
                         float* __restrict__ out)
{
    out[0] = loss_sum[0] / (float)num_pos[0];
}

// ---------------- launch ---------------------------------------------------
extern "C" void kernel_launch(void* const* d_in, const int* in_sizes, int n_in,
                              void* d_out, int out_size, void* d_ws, size_t ws_size,
                              hipStream_t stream)
{
    const float* feat = (const float*)d_in[0];
    const int*   gt   = (const int*)d_in[1];
    float*       out  = (float*)d_out;

    char* ws = (char*)d_ws;
    unsigned* num_pos  = (unsigned*)(ws + 0);
    float*    loss_sum = (float*)(ws + 4);
    float*    k0p      = (float*)(ws + 256);    // [32][64]
    float*    k0n      = (float*)(ws + 8448);   // [19][64]
    unsigned* pm       = (unsigned*)(ws + 65536);

    hipMemsetAsync(d_ws, 0, 16384, stream);   // zero num_pos/loss_sum/k0p

    k1_proto<<<G1, 256, 0, stream>>>(feat, gt, pm, k0p, num_pos);
    k2_norm <<<1,  256, 0, stream>>>(k0p, k0n);
    k3_loss <<<NPIX / 1024, 256, 0, stream>>>(feat, gt, pm, k0n, loss_sum);
    k4_final<<<1, 1, 0, stream>>>(loss_sum, num_pos, out);
}